// Round 3
// baseline (536.028 us; speedup 1.0000x reference)
//
#include <hip/hip_runtime.h>

// Apply a 2-qubit gate on qubits (5,12) of a 24-qubit state, batch=4 innermost.
// Element flat index: idx = b + 4*(q23 + 2*q22 + ... + 2^23*q0)
//   => qubit k stride = 2^(25-k) elements: q5 -> bit 20, q12 -> bit 13.
// Each thread owns 2 consecutive float4s (32 B) at each of the 4 (q5,q12)
// combos. All state traffic is nontemporal (pure stream, zero reuse).

#define Q12_STRIDE 8192u      // 2^13 elements
#define Q5_STRIDE  1048576u   // 2^20 elements

// Native clang vector type — required by __builtin_nontemporal_{load,store}
// (HIP_vector_type float4 is a class and is rejected).
typedef float vf4 __attribute__((ext_vector_type(4)));

__global__ __launch_bounds__(256) void quantum_gate_2q_kernel(
    const float* __restrict__ in,
    const float* __restrict__ gate,
    float* __restrict__ out)
{
    // 2^21 threads total; each covers 8 contiguous elements (2 float4s).
    unsigned t = blockIdx.x * blockDim.x + threadIdx.x;
    unsigned u = t << 3;  // compressed element index (support bits removed)
    // Insert zero bits at bit 13 (q12) and bit 20 (q5):
    // bits [0,12] stay; bits [13,18] shift up 1; bits [19,23] shift up 2.
    unsigned base = (u & 0x1FFFu) | ((u & 0x07E000u) << 1) | ((u & 0xF80000u) << 2);

    const vf4* __restrict__ in4 = (const vf4*)in;
    vf4* __restrict__ out4 = (vf4*)out;
    unsigned b = base >> 2;

    // Gate loads are wave-uniform -> scalar loads, L1-resident.
    float g[16];
#pragma unroll
    for (int i = 0; i < 16; ++i) g[i] = gate[i];

#pragma unroll
    for (int j = 0; j < 2; ++j) {
        unsigned bj = b + j;
        // s[k], k = q5*2 + q12 (gate in-axis order: axis2<->q5, axis3<->q12)
        vf4 s0 = __builtin_nontemporal_load(&in4[bj]);
        vf4 s1 = __builtin_nontemporal_load(&in4[bj + (Q12_STRIDE >> 2)]);
        vf4 s2 = __builtin_nontemporal_load(&in4[bj + (Q5_STRIDE >> 2)]);
        vf4 s3 = __builtin_nontemporal_load(&in4[bj + ((Q5_STRIDE + Q12_STRIDE) >> 2)]);

        vf4 r0, r1, r2, r3;
        r0 = g[0]*s0 + g[1]*s1 + g[2]*s2 + g[3]*s3;
        r1 = g[4]*s0 + g[5]*s1 + g[6]*s2 + g[7]*s3;
        r2 = g[8]*s0 + g[9]*s1 + g[10]*s2 + g[11]*s3;
        r3 = g[12]*s0 + g[13]*s1 + g[14]*s2 + g[15]*s3;

        __builtin_nontemporal_store(r0, &out4[bj]);
        __builtin_nontemporal_store(r1, &out4[bj + (Q12_STRIDE >> 2)]);
        __builtin_nontemporal_store(r2, &out4[bj + (Q5_STRIDE >> 2)]);
        __builtin_nontemporal_store(r3, &out4[bj + ((Q5_STRIDE + Q12_STRIDE) >> 2)]);
    }
}

extern "C" void kernel_launch(void* const* d_in, const int* in_sizes, int n_in,
                              void* d_out, int out_size, void* d_ws, size_t ws_size,
                              hipStream_t stream) {
    const float* state = (const float*)d_in[0];
    const float* gate  = (const float*)d_in[1];
    float* out = (float*)d_out;

    // 2^24 * 4 elements total; 4 combos x 8 contiguous elements per thread
    // => 2^21 threads = 8192 blocks x 256.
    const int threads = 256;
    const int blocks = (1 << 21) / threads;
    quantum_gate_2q_kernel<<<blocks, threads, 0, stream>>>(state, gate, out);
}